// Round 6
// baseline (536.303 us; speedup 1.0000x reference)
//
#include <hip/hip_runtime.h>
#include <hip/hip_bf16.h>
#include <stdint.h>

typedef short bf16x8 __attribute__((ext_vector_type(8)));
typedef float f32x4 __attribute__((ext_vector_type(4)));
typedef unsigned short ushort_t;
typedef unsigned int uint_t;

#define CIN   256
#define COUT  256
#define HWDIM 56
#define IMG   (HWDIM * HWDIM)   // 3136
#define K_TOT (CIN * 9)         // 2304
#define NIMG  32
#define NPIX  (NIMG * IMG)      // 100352
#define BM    256
#define BN    256
#define NCHUNK 36                // 18 steps x 2 half-chunks of 64 ch

#define AS1CAST(p) ((const __attribute__((address_space(1))) unsigned int*)(uintptr_t)(p))
#define AS3CAST(p) ((__attribute__((address_space(3))) unsigned int*)(uintptr_t)(p))

__device__ __forceinline__ ushort_t f2bf(float f) {
    union { float f; uint_t u; } v; v.f = f;
    uint_t u = v.u;
    uint_t r = u + 0x7FFFu + ((u >> 16) & 1u);   // RNE
    return (ushort_t)(r >> 16);
}

// ---------------------------------------------------------------------------
// Ternarize: per-filter delta/alpha; signs as exact bf16 into wt2[o][kpos][c].
// Block 0 also zeroes the xt halo pad row (row NPIX).
// ---------------------------------------------------------------------------
__global__ __launch_bounds__(256) void ternarize_kernel(
        const float* __restrict__ w,
        ushort_t* __restrict__ wt2,
        float* __restrict__ alpha_out,
        ushort_t* __restrict__ xt_pad_row) {
    const int o = blockIdx.x;
    const int t = threadIdx.x;
    const int lane = t & 63;
    const int wv = t >> 6;
    const float* base = w + (size_t)o * K_TOT;

    if (o == 0 && t < 32) ((uint4*)xt_pad_row)[t] = (uint4){0u, 0u, 0u, 0u};

    float v[9];
#pragma unroll
    for (int i = 0; i < 9; ++i) v[i] = base[t + 256 * i];

    __shared__ float sred[8];

    float s = 0.f;
#pragma unroll
    for (int i = 0; i < 9; ++i) s += fabsf(v[i]);
#pragma unroll
    for (int off = 32; off > 0; off >>= 1) s += __shfl_down(s, off);
    if (lane == 0) sred[wv] = s;
    __syncthreads();
    if (t == 0) sred[0] = sred[0] + sred[1] + sred[2] + sred[3];
    __syncthreads();
    const float delta = (0.7f / (float)K_TOT) * sred[0];
    __syncthreads();

    float asum = 0.f, cnt = 0.f;
#pragma unroll
    for (int i = 0; i < 9; ++i) {
        float a = fabsf(v[i]);
        if (a > delta) { asum += a; cnt += 1.f; }
    }
#pragma unroll
    for (int off = 32; off > 0; off >>= 1) {
        asum += __shfl_down(asum, off);
        cnt  += __shfl_down(cnt, off);
    }
    if (lane == 0) { sred[wv] = asum; sred[4 + wv] = cnt; }
    __syncthreads();
    if (t == 0) {
        float at = sred[0] + sred[1] + sred[2] + sred[3];
        float ct = sred[4] + sred[5] + sred[6] + sred[7];
        alpha_out[o] = at / ct;
    }

#pragma unroll
    for (int i = 0; i < 9; ++i) {
        int idx = t + 256 * i;           // flat k = c*9 + r
        int c = idx / 9;
        int r = idx - c * 9;
        float x = v[i];
        ushort_t bits = 0;
        if (x > delta)       bits = 0x3F80u;
        else if (x < -delta) bits = 0xBF80u;
        wt2[(size_t)o * K_TOT + r * 256 + c] = bits;
    }
}

// ---------------------------------------------------------------------------
// Transpose + convert: x NCHW fp32 -> xt [pixel][channel] bf16.
// ---------------------------------------------------------------------------
__global__ __launch_bounds__(256) void transpose_kernel(
        const float* __restrict__ x, ushort_t* __restrict__ xt) {
    __shared__ float L[32][132];
    const int hw0 = blockIdx.x * 32;
    const int c0  = blockIdx.y * 128;
    const int n   = blockIdx.z;
    const int t = threadIdx.x;
    const int c_ = t >> 1;        // 0..127
    const int half = t & 1;

    const float* src = x + (size_t)(n * CIN + c0 + c_) * IMG + hw0 + half * 16;
    float4 v[4];
#pragma unroll
    for (int k = 0; k < 4; ++k) v[k] = *(const float4*)(src + k * 4);
#pragma unroll
    for (int k = 0; k < 4; ++k) {
        L[half * 16 + k * 4 + 0][c_] = v[k].x;
        L[half * 16 + k * 4 + 1][c_] = v[k].y;
        L[half * 16 + k * 4 + 2][c_] = v[k].z;
        L[half * 16 + k * 4 + 3][c_] = v[k].w;
    }
    __syncthreads();

    const int seg = t & 15;       // 8-channel segment
    const int hwb = t >> 4;       // 0..15
#pragma unroll
    for (int j = 0; j < 2; ++j) {
        const int hwl = hwb + j * 16;
        const float2* row = (const float2*)&L[hwl][seg * 8];
        uint_t pk[4];
#pragma unroll
        for (int q = 0; q < 4; ++q) {
            float2 f = row[q];
            pk[q] = (uint_t)f2bf(f.x) | ((uint_t)f2bf(f.y) << 16);
        }
        *(uint4*)&xt[(size_t)(n * IMG + hw0 + hwl) * CIN + c0 + seg * 8] =
            (uint4){pk[0], pk[1], pk[2], pk[3]};
    }
}

// ---------------------------------------------------------------------------
// Implicit-GEMM conv, 256x256 tile, 8 waves (2M x 4N, wave tile 128x64).
// 36 chunks of {one kpos x 64 ch}; 2 LDS slots by chunk parity (32 KB each
// per operand -> 128 KB total, 1 block/CU, 8 waves = 2/SIMD).
// Per chunk c (slot P = c&1):
//   vmcnt(8); barrier      // chunk c landed (every wave passed its own vmcnt)
//   READ 24 frags (slot P) // fa0/fa1[8], fx0/fx1[4]
//   MFMA k0 x32            // compiler-inserted lgkmcnt: reads drain under it
//   lgkm(0); barrier       // certificate: ALL waves' slot-P reads complete
//   STAGE chunk c+2 -> P   // 8 global_load_lds; provably safe overwrite
//   MFMA k1 x32            // frags already in regs; overlaps stage issue
// Tail: chunk 34 (vmcnt(8), no stage), chunk 35 (vmcnt(0), no stage);
// ledger: 16 outstanding steady, closes at 0. No dummy restages.
// ---------------------------------------------------------------------------
__global__ __launch_bounds__(512, 2) void tern_conv_kernel(
        const ushort_t* __restrict__ xt,    // [(NPIX+1)][256]
        const ushort_t* __restrict__ wt2,   // [256 o][9][256 c]
        const float* __restrict__ alpha,
        const float* __restrict__ bias,
        float* __restrict__ out) {
    __shared__ __align__(16) ushort_t As[2][BM * 64];   // 2 x 32 KB
    __shared__ __align__(16) ushort_t Xs[2][BN * 64];   // 2 x 32 KB

    const int tid = threadIdx.x;          // 0..511
    const int wv = tid >> 6;              // 0..7
    const int l = tid & 63;
    const int p0 = blockIdx.x * BN;

    const int rthr = tid >> 3;                 // 0..63: staging row within a round
    const int g = (l & 7) ^ ((l >> 3) & 7);    // swizzled source 8-ch segment

    // per-thread staging sources: 4 row-slots, stride 64
    const ushort_t* abase[4];
    int ximg[4], xh[4], xw[4];
#pragma unroll
    for (int i = 0; i < 4; ++i) {
        abase[i] = wt2 + (size_t)(i * 64 + rthr) * K_TOT + g * 8;
        int p = p0 + i * 64 + rthr;
        int n_img = p / IMG;
        int hw_ = p - n_img * IMG;
        xh[i] = hw_ / HWDIM;
        xw[i] = hw_ - xh[i] * HWDIM;
        ximg[i] = n_img * IMG;
    }

    // wave-uniform LDS staging destinations (element offsets); lane adds l*16B
    int doff[4];
#pragma unroll
    for (int i = 0; i < 4; ++i) doff[i] = (i * 64 + wv * 8) * 64;

    // fragment-read geometry: wave tile 128x64 at (wm, wn)
    const int qd = l >> 4, ln = l & 15;
    const int wm = (wv >> 2) * 128;            // 0 or 128
    const int wn = (wv & 3) * 64;              // 0,64,128,192
    const int so0 = (qd ^ (ln & 7)) * 8;       // de-swizzle; k-half 1 is so0^32
    int arow[8], xrow[4];
#pragma unroll
    for (int i = 0; i < 8; ++i) arow[i] = (wm + i * 16 + ln) * 64;
#pragma unroll
    for (int j = 0; j < 4; ++j) xrow[j] = (wn + j * 16 + ln) * 64;

    f32x4 acc[8][4];
#pragma unroll
    for (int i = 0; i < 8; ++i)
#pragma unroll
        for (int j = 0; j < 4; ++j)
            acc[i][j] = (f32x4){0.f, 0.f, 0.f, 0.f};

    bf16x8 fa0[8], fa1[8], fx0[4], fx1[4];

#define STAGE_CHUNK(c, SLOT) do {                                               \
    const int st_ = (c) >> 1, hs_ = (c) & 1;                                    \
    const int c0_ = (st_ >= 9) ? 128 : 0;                                       \
    const int kp_ = st_ - ((st_ >= 9) ? 9 : 0);                                 \
    const int dh_ = kp_ / 3 - 1;                                                \
    const int dw_ = kp_ - (dh_ + 1) * 3 - 1;                                    \
    const int aoff_ = kp_ * 256 + c0_ + hs_ * 64;                               \
    _Pragma("unroll")                                                           \
    for (int i = 0; i < 4; ++i)                                                 \
        __builtin_amdgcn_global_load_lds(AS1CAST(abase[i] + aoff_),             \
                                         AS3CAST(&As[SLOT][doff[i]]), 16, 0, 0);\
    _Pragma("unroll")                                                           \
    for (int i = 0; i < 4; ++i) {                                               \
        int h2_ = xh[i] + dh_, w2_ = xw[i] + dw_;                               \
        int row_ = ((unsigned)h2_ < (unsigned)HWDIM &&                          \
                    (unsigned)w2_ < (unsigned)HWDIM)                            \
                       ? (ximg[i] + h2_ * HWDIM + w2_) : NPIX;                  \
        __builtin_amdgcn_global_load_lds(                                       \
            AS1CAST(xt + (size_t)row_ * CIN + c0_ + hs_ * 64 + g * 8),          \
            AS3CAST(&Xs[SLOT][doff[i]]), 16, 0, 0);                             \
    }                                                                           \
} while (0)

#define READ_FRAGS(P) do {                                                      \
    _Pragma("unroll")                                                           \
    for (int m = 0; m < 8; ++m) {                                               \
        fa0[m] = *(const bf16x8*)&As[P][arow[m] + so0];                         \
        fa1[m] = *(const bf16x8*)&As[P][arow[m] + (so0 ^ 32)];                  \
    }                                                                           \
    _Pragma("unroll")                                                           \
    for (int n = 0; n < 4; ++n) {                                               \
        fx0[n] = *(const bf16x8*)&Xs[P][xrow[n] + so0];                         \
        fx1[n] = *(const bf16x8*)&Xs[P][xrow[n] + (so0 ^ 32)];                  \
    }                                                                           \
} while (0)

#define MFMA_K0 do {                                                            \
    __builtin_amdgcn_s_setprio(1);                                              \
    _Pragma("unroll")                                                           \
    for (int m = 0; m < 8; ++m)                                                 \
        _Pragma("unroll")                                                       \
        for (int n = 0; n < 4; ++n)                                             \
            acc[m][n] = __builtin_amdgcn_mfma_f32_16x16x32_bf16(                \
                fa0[m], fx0[n], acc[m][n], 0, 0, 0);                            \
    __builtin_amdgcn_s_setprio(0);                                              \
} while (0)

#define MFMA_K1 do {                                                            \
    __builtin_amdgcn_s_setprio(1);                                              \
    _Pragma("unroll")                                                           \
    for (int m = 0; m < 8; ++m)                                                 \
        _Pragma("unroll")                                                       \
        for (int n = 0; n < 4; ++n)                                             \
            acc[m][n] = __builtin_amdgcn_mfma_f32_16x16x32_bf16(                \
                fa1[m], fx1[n], acc[m][n], 0, 0, 0);                            \
    __builtin_amdgcn_s_setprio(0);                                              \
} while (0)

#define CHUNK_FULL(k, P) do {                                                   \
    asm volatile("s_waitcnt vmcnt(8)" ::: "memory");                            \
    __builtin_amdgcn_s_barrier();                                               \
    asm volatile("" ::: "memory");                                              \
    READ_FRAGS(P);                                                              \
    MFMA_K0;                                                                    \
    asm volatile("s_waitcnt lgkmcnt(0)" ::: "memory");                          \
    __builtin_amdgcn_s_barrier();                                               \
    asm volatile("" ::: "memory");                                              \
    STAGE_CHUNK((k) + 2, P);                                                    \
    MFMA_K1;                                                                    \
} while (0)

#define CHUNK_TAIL(P, VM) do {                                                  \
    asm volatile("s_waitcnt vmcnt(" #VM ")" ::: "memory");                      \
    __builtin_amdgcn_s_barrier();                                               \
    asm volatile("" ::: "memory");                                              \
    READ_FRAGS(P);                                                              \
    MFMA_K0;                                                                    \
    MFMA_K1;                                                                    \
} while (0)

    // ---- prologue: stage chunks 0,1 (16 outstanding)
    STAGE_CHUNK(0, 0);
    STAGE_CHUNK(1, 1);

    // ---- chunks 0..33 stage c+2; 34/35 drain
    CHUNK_FULL(0, 0);
#pragma unroll 1
    for (int k = 1; k < 33; k += 2) {
        CHUNK_FULL(k, 1);
        CHUNK_FULL(k + 1, 0);
    }
    CHUNK_FULL(33, 1);                         // stages chunk 35
    CHUNK_TAIL(0, 8);                          // chunk 34: drains its batch
    CHUNK_TAIL(1, 0);                          // chunk 35: ledger closes at 0

#undef CHUNK_TAIL
#undef CHUNK_FULL
#undef MFMA_K1
#undef MFMA_K0
#undef READ_FRAGS
#undef STAGE_CHUNK

    // epilogue: out[n][o][h][w] = alpha[o]*acc + bias[o]
#pragma unroll
    for (int im = 0; im < 8; ++im) {
        const int orow = wm + im * 16 + qd * 4;
        const f32x4 al = *(const f32x4*)&alpha[orow];
        const f32x4 bi = *(const f32x4*)&bias[orow];
#pragma unroll
        for (int in2 = 0; in2 < 4; ++in2) {
            const int pc = p0 + wn + in2 * 16 + ln;
            const int ni = pc / IMG;
            const int hwc = pc - ni * IMG;
            const size_t obase = (size_t)ni * COUT * IMG + hwc;
#pragma unroll
            for (int rr = 0; rr < 4; ++rr)
                out[obase + (size_t)(orow + rr) * IMG] = al[rr] * acc[im][in2][rr] + bi[rr];
        }
    }
}

extern "C" void kernel_launch(void* const* d_in, const int* in_sizes, int n_in,
                              void* d_out, int out_size, void* d_ws, size_t ws_size,
                              hipStream_t stream) {
    const float* x      = (const float*)d_in[0];
    const float* weight = (const float*)d_in[1];
    const float* bias   = (const float*)d_in[2];
    float* out = (float*)d_out;

    // workspace: xt (NPIX+1)*256 bf16 (last row = zero halo), wt2, alpha
    ushort_t* xt     = (ushort_t*)d_ws;
    ushort_t* wt2    = (ushort_t*)((char*)d_ws + (size_t)(NPIX + 1) * CIN * sizeof(ushort_t));
    float*    alphav = (float*)((char*)wt2 + (size_t)COUT * K_TOT * sizeof(ushort_t));

    ternarize_kernel<<<COUT, 256, 0, stream>>>(weight, wt2, alphav,
                                               xt + (size_t)NPIX * CIN);

    dim3 tg(IMG / 32, CIN / 128, NIMG);  // 98 x 2 x 32
    transpose_kernel<<<tg, 256, 0, stream>>>(x, xt);

    const int n_blocks = NPIX / BN;      // 392
    tern_conv_kernel<<<n_blocks, 512, 0, stream>>>(xt, wt2, alphav, bias, out);
}

// Round 7
// 488.487 us; speedup vs baseline: 1.0979x; 1.0979x over previous
//
#include <hip/hip_runtime.h>
#include <hip/hip_bf16.h>
#include <stdint.h>

typedef short bf16x8 __attribute__((ext_vector_type(8)));
typedef float f32x4 __attribute__((ext_vector_type(4)));
typedef unsigned short ushort_t;
typedef unsigned int uint_t;

#define CIN   256
#define COUT  256
#define HWDIM 56
#define IMG   (HWDIM * HWDIM)   // 3136
#define K_TOT (CIN * 9)         // 2304
#define NIMG  32
#define NPIX  (NIMG * IMG)      // 100352
#define BM    256
#define BN    256
#define NCHUNK 36                // 18 steps x 2 half-chunks of 64 ch

#define AS1CAST(p) ((const __attribute__((address_space(1))) unsigned int*)(uintptr_t)(p))
#define AS3CAST(p) ((__attribute__((address_space(3))) unsigned int*)(uintptr_t)(p))

__device__ __forceinline__ ushort_t f2bf(float f) {
    union { float f; uint_t u; } v; v.f = f;
    uint_t u = v.u;
    uint_t r = u + 0x7FFFu + ((u >> 16) & 1u);   // RNE
    return (ushort_t)(r >> 16);
}

// ---------------------------------------------------------------------------
// Ternarize: per-filter delta/alpha; signs as exact bf16 into wt2[o][kpos][c].
// Block 0 also zeroes the xt halo pad row (row NPIX).
// ---------------------------------------------------------------------------
__global__ __launch_bounds__(256) void ternarize_kernel(
        const float* __restrict__ w,
        ushort_t* __restrict__ wt2,
        float* __restrict__ alpha_out,
        ushort_t* __restrict__ xt_pad_row) {
    const int o = blockIdx.x;
    const int t = threadIdx.x;
    const int lane = t & 63;
    const int wv = t >> 6;
    const float* base = w + (size_t)o * K_TOT;

    if (o == 0 && t < 32) ((uint4*)xt_pad_row)[t] = (uint4){0u, 0u, 0u, 0u};

    float v[9];
#pragma unroll
    for (int i = 0; i < 9; ++i) v[i] = base[t + 256 * i];

    __shared__ float sred[8];

    float s = 0.f;
#pragma unroll
    for (int i = 0; i < 9; ++i) s += fabsf(v[i]);
#pragma unroll
    for (int off = 32; off > 0; off >>= 1) s += __shfl_down(s, off);
    if (lane == 0) sred[wv] = s;
    __syncthreads();
    if (t == 0) sred[0] = sred[0] + sred[1] + sred[2] + sred[3];
    __syncthreads();
    const float delta = (0.7f / (float)K_TOT) * sred[0];
    __syncthreads();

    float asum = 0.f, cnt = 0.f;
#pragma unroll
    for (int i = 0; i < 9; ++i) {
        float a = fabsf(v[i]);
        if (a > delta) { asum += a; cnt += 1.f; }
    }
#pragma unroll
    for (int off = 32; off > 0; off >>= 1) {
        asum += __shfl_down(asum, off);
        cnt  += __shfl_down(cnt, off);
    }
    if (lane == 0) { sred[wv] = asum; sred[4 + wv] = cnt; }
    __syncthreads();
    if (t == 0) {
        float at = sred[0] + sred[1] + sred[2] + sred[3];
        float ct = sred[4] + sred[5] + sred[6] + sred[7];
        alpha_out[o] = at / ct;
    }

#pragma unroll
    for (int i = 0; i < 9; ++i) {
        int idx = t + 256 * i;           // flat k = c*9 + r
        int c = idx / 9;
        int r = idx - c * 9;
        float x = v[i];
        ushort_t bits = 0;
        if (x > delta)       bits = 0x3F80u;
        else if (x < -delta) bits = 0xBF80u;
        wt2[(size_t)o * K_TOT + r * 256 + c] = bits;
    }
}

// ---------------------------------------------------------------------------
// Transpose + convert: x NCHW fp32 -> xt [pixel][channel] bf16.
// ---------------------------------------------------------------------------
__global__ __launch_bounds__(256) void transpose_kernel(
        const float* __restrict__ x, ushort_t* __restrict__ xt) {
    __shared__ float L[32][132];
    const int hw0 = blockIdx.x * 32;
    const int c0  = blockIdx.y * 128;
    const int n   = blockIdx.z;
    const int t = threadIdx.x;
    const int c_ = t >> 1;        // 0..127
    const int half = t & 1;

    const float* src = x + (size_t)(n * CIN + c0 + c_) * IMG + hw0 + half * 16;
    float4 v[4];
#pragma unroll
    for (int k = 0; k < 4; ++k) v[k] = *(const float4*)(src + k * 4);
#pragma unroll
    for (int k = 0; k < 4; ++k) {
        L[half * 16 + k * 4 + 0][c_] = v[k].x;
        L[half * 16 + k * 4 + 1][c_] = v[k].y;
        L[half * 16 + k * 4 + 2][c_] = v[k].z;
        L[half * 16 + k * 4 + 3][c_] = v[k].w;
    }
    __syncthreads();

    const int seg = t & 15;       // 8-channel segment
    const int hwb = t >> 4;       // 0..15
#pragma unroll
    for (int j = 0; j < 2; ++j) {
        const int hwl = hwb + j * 16;
        const float2* row = (const float2*)&L[hwl][seg * 8];
        uint_t pk[4];
#pragma unroll
        for (int q = 0; q < 4; ++q) {
            float2 f = row[q];
            pk[q] = (uint_t)f2bf(f.x) | ((uint_t)f2bf(f.y) << 16);
        }
        *(uint4*)&xt[(size_t)(n * IMG + hw0 + hwl) * CIN + c0 + seg * 8] =
            (uint4){pk[0], pk[1], pk[2], pk[3]};
    }
}

// ---------------------------------------------------------------------------
// Implicit-GEMM conv, 256x256 tile, 8 waves (2M x 4N, wave tile 128x64).
// 36 chunks of {one kpos x 64 ch}; 2 LDS slots by chunk parity; 128 KB LDS,
// 1 block/CU (8 waves = 2/SIMD) -> VGPR cap 256 (launch_bounds 512,1).
// Register discipline: only ONE 48-VGPR frag set live at a time:
//   vmcnt(8); barrier      // chunk c landed
//   READ0 (12 frags, k0)   // slot P
//   MFMA_K0 x32            // fa1 set not yet read -> peak ~221 VGPR
//   READ1 (12 frags, k1)   // slot P
//   lgkm(0); barrier       // certificate: ALL waves' slot-P reads complete
//   STAGE chunk c+2 -> P   // safe overwrite
//   MFMA_K1 x32
// Tail: chunk 34 (vmcnt(8)), 35 (vmcnt(0)); ledger 16 steady, closes at 0.
// ---------------------------------------------------------------------------
__global__ __launch_bounds__(512, 1) void tern_conv_kernel(
        const ushort_t* __restrict__ xt,    // [(NPIX+1)][256]
        const ushort_t* __restrict__ wt2,   // [256 o][9][256 c]
        const float* __restrict__ alpha,
        const float* __restrict__ bias,
        float* __restrict__ out) {
    __shared__ __align__(16) ushort_t As[2][BM * 64];   // 2 x 32 KB
    __shared__ __align__(16) ushort_t Xs[2][BN * 64];   // 2 x 32 KB

    const int tid = threadIdx.x;          // 0..511
    const int wv = tid >> 6;              // 0..7
    const int l = tid & 63;
    const int p0 = blockIdx.x * BN;

    const int rthr = tid >> 3;                 // 0..63: staging row within a round
    const int g = (l & 7) ^ ((l >> 3) & 7);    // swizzled source 8-ch segment

    // per-thread staging sources: 4 row-slots, stride 64
    const ushort_t* abase[4];
    int ximg[4], xh[4], xw[4];
#pragma unroll
    for (int i = 0; i < 4; ++i) {
        abase[i] = wt2 + (size_t)(i * 64 + rthr) * K_TOT + g * 8;
        int p = p0 + i * 64 + rthr;
        int n_img = p / IMG;
        int hw_ = p - n_img * IMG;
        xh[i] = hw_ / HWDIM;
        xw[i] = hw_ - xh[i] * HWDIM;
        ximg[i] = n_img * IMG;
    }

    // wave-uniform LDS staging destinations (element offsets); lane adds l*16B
    int doff[4];
#pragma unroll
    for (int i = 0; i < 4; ++i) doff[i] = (i * 64 + wv * 8) * 64;

    // fragment-read geometry: wave tile 128x64 at (wm, wn)
    const int qd = l >> 4, ln = l & 15;
    const int wm = (wv >> 2) * 128;            // 0 or 128
    const int wn = (wv & 3) * 64;              // 0,64,128,192
    const int so0 = (qd ^ (ln & 7)) * 8;       // de-swizzle; k-half 1 is so0^32
    int arow[8], xrow[4];
#pragma unroll
    for (int i = 0; i < 8; ++i) arow[i] = (wm + i * 16 + ln) * 64;
#pragma unroll
    for (int j = 0; j < 4; ++j) xrow[j] = (wn + j * 16 + ln) * 64;

    f32x4 acc[8][4];
#pragma unroll
    for (int i = 0; i < 8; ++i)
#pragma unroll
        for (int j = 0; j < 4; ++j)
            acc[i][j] = (f32x4){0.f, 0.f, 0.f, 0.f};

    bf16x8 fa0[8], fx0[4];   // k-half 0 frags
    bf16x8 fa1[8], fx1[4];   // k-half 1 frags (live only after MFMA_K0)

#define STAGE_CHUNK(c, SLOT) do {                                               \
    const int st_ = (c) >> 1, hs_ = (c) & 1;                                    \
    const int c0_ = (st_ >= 9) ? 128 : 0;                                       \
    const int kp_ = st_ - ((st_ >= 9) ? 9 : 0);                                 \
    const int dh_ = kp_ / 3 - 1;                                                \
    const int dw_ = kp_ - (dh_ + 1) * 3 - 1;                                    \
    const int aoff_ = kp_ * 256 + c0_ + hs_ * 64;                               \
    _Pragma("unroll")                                                           \
    for (int i = 0; i < 4; ++i)                                                 \
        __builtin_amdgcn_global_load_lds(AS1CAST(abase[i] + aoff_),             \
                                         AS3CAST(&As[SLOT][doff[i]]), 16, 0, 0);\
    _Pragma("unroll")                                                           \
    for (int i = 0; i < 4; ++i) {                                               \
        int h2_ = xh[i] + dh_, w2_ = xw[i] + dw_;                               \
        int row_ = ((unsigned)h2_ < (unsigned)HWDIM &&                          \
                    (unsigned)w2_ < (unsigned)HWDIM)                            \
                       ? (ximg[i] + h2_ * HWDIM + w2_) : NPIX;                  \
        __builtin_amdgcn_global_load_lds(                                       \
            AS1CAST(xt + (size_t)row_ * CIN + c0_ + hs_ * 64 + g * 8),          \
            AS3CAST(&Xs[SLOT][doff[i]]), 16, 0, 0);                             \
    }                                                                           \
} while (0)

#define READ0(P) do {                                                           \
    _Pragma("unroll")                                                           \
    for (int m = 0; m < 8; ++m)                                                 \
        fa0[m] = *(const bf16x8*)&As[P][arow[m] + so0];                         \
    _Pragma("unroll")                                                           \
    for (int n = 0; n < 4; ++n)                                                 \
        fx0[n] = *(const bf16x8*)&Xs[P][xrow[n] + so0];                         \
} while (0)

#define READ1(P) do {                                                           \
    _Pragma("unroll")                                                           \
    for (int m = 0; m < 8; ++m)                                                 \
        fa1[m] = *(const bf16x8*)&As[P][arow[m] + (so0 ^ 32)];                  \
    _Pragma("unroll")                                                           \
    for (int n = 0; n < 4; ++n)                                                 \
        fx1[n] = *(const bf16x8*)&Xs[P][xrow[n] + (so0 ^ 32)];                  \
} while (0)

#define MFMA_K0 do {                                                            \
    __builtin_amdgcn_s_setprio(1);                                              \
    _Pragma("unroll")                                                           \
    for (int m = 0; m < 8; ++m)                                                 \
        _Pragma("unroll")                                                       \
        for (int n = 0; n < 4; ++n)                                             \
            acc[m][n] = __builtin_amdgcn_mfma_f32_16x16x32_bf16(                \
                fa0[m], fx0[n], acc[m][n], 0, 0, 0);                            \
    __builtin_amdgcn_s_setprio(0);                                              \
} while (0)

#define MFMA_K1 do {                                                            \
    __builtin_amdgcn_s_setprio(1);                                              \
    _Pragma("unroll")                                                           \
    for (int m = 0; m < 8; ++m)                                                 \
        _Pragma("unroll")                                                       \
        for (int n = 0; n < 4; ++n)                                             \
            acc[m][n] = __builtin_amdgcn_mfma_f32_16x16x32_bf16(                \
                fa1[m], fx1[n], acc[m][n], 0, 0, 0);                            \
    __builtin_amdgcn_s_setprio(0);                                              \
} while (0)

#define CHUNK_FULL(k, P) do {                                                   \
    asm volatile("s_waitcnt vmcnt(8)" ::: "memory");                            \
    __builtin_amdgcn_s_barrier();                                               \
    asm volatile("" ::: "memory");                                              \
    READ0(P);                                                                   \
    MFMA_K0;                                                                    \
    READ1(P);                                                                   \
    asm volatile("s_waitcnt lgkmcnt(0)" ::: "memory");                          \
    __builtin_amdgcn_s_barrier();                                               \
    asm volatile("" ::: "memory");                                              \
    STAGE_CHUNK((k) + 2, P);                                                    \
    MFMA_K1;                                                                    \
} while (0)

#define CHUNK_TAIL(P, VM) do {                                                  \
    asm volatile("s_waitcnt vmcnt(" #VM ")" ::: "memory");                      \
    __builtin_amdgcn_s_barrier();                                               \
    asm volatile("" ::: "memory");                                              \
    READ0(P);                                                                   \
    MFMA_K0;                                                                    \
    READ1(P);                                                                   \
    MFMA_K1;                                                                    \
} while (0)

    // ---- prologue: stage chunks 0,1 (16 outstanding)
    STAGE_CHUNK(0, 0);
    STAGE_CHUNK(1, 1);

    // ---- chunks 0..33 stage c+2; 34/35 drain
    CHUNK_FULL(0, 0);
#pragma unroll 1
    for (int k = 1; k < 33; k += 2) {
        CHUNK_FULL(k, 1);
        CHUNK_FULL(k + 1, 0);
    }
    CHUNK_FULL(33, 1);                         // stages chunk 35
    CHUNK_TAIL(0, 8);                          // chunk 34: drains its batch
    CHUNK_TAIL(1, 0);                          // chunk 35: ledger closes at 0

#undef CHUNK_TAIL
#undef CHUNK_FULL
#undef MFMA_K1
#undef MFMA_K0
#undef READ1
#undef READ0
#undef STAGE_CHUNK

    // epilogue: out[n][o][h][w] = alpha[o]*acc + bias[o]
#pragma unroll
    for (int im = 0; im < 8; ++im) {
        const int orow = wm + im * 16 + qd * 4;
        const f32x4 al = *(const f32x4*)&alpha[orow];
        const f32x4 bi = *(const f32x4*)&bias[orow];
#pragma unroll
        for (int in2 = 0; in2 < 4; ++in2) {
            const int pc = p0 + wn + in2 * 16 + ln;
            const int ni = pc / IMG;
            const int hwc = pc - ni * IMG;
            const size_t obase = (size_t)ni * COUT * IMG + hwc;
#pragma unroll
            for (int rr = 0; rr < 4; ++rr)
                out[obase + (size_t)(orow + rr) * IMG] = al[rr] * acc[im][in2][rr] + bi[rr];
        }
    }
}

extern "C" void kernel_launch(void* const* d_in, const int* in_sizes, int n_in,
                              void* d_out, int out_size, void* d_ws, size_t ws_size,
                              hipStream_t stream) {
    const float* x      = (const float*)d_in[0];
    const float* weight = (const float*)d_in[1];
    const float* bias   = (const float*)d_in[2];
    float* out = (float*)d_out;

    // workspace: xt (NPIX+1)*256 bf16 (last row = zero halo), wt2, alpha
    ushort_t* xt     = (ushort_t*)d_ws;
    ushort_t* wt2    = (ushort_t*)((char*)d_ws + (size_t)(NPIX + 1) * CIN * sizeof(ushort_t));
    float*    alphav = (float*)((char*)wt2 + (size_t)COUT * K_TOT * sizeof(ushort_t));

    ternarize_kernel<<<COUT, 256, 0, stream>>>(weight, wt2, alphav,
                                               xt + (size_t)NPIX * CIN);

    dim3 tg(IMG / 32, CIN / 128, NIMG);  // 98 x 2 x 32
    transpose_kernel<<<tg, 256, 0, stream>>>(x, xt);

    const int n_blocks = NPIX / BN;      // 392
    tern_conv_kernel<<<n_blocks, 512, 0, stream>>>(xt, wt2, alphav, bias, out);
}

// Round 9
// 315.357 us; speedup vs baseline: 1.7006x; 1.5490x over previous
//
#include <hip/hip_runtime.h>
#include <hip/hip_bf16.h>
#include <stdint.h>

typedef short bf16x8 __attribute__((ext_vector_type(8)));
typedef float f32x4 __attribute__((ext_vector_type(4)));
typedef unsigned short ushort_t;
typedef unsigned int uint_t;

#define CIN   256
#define COUT  256
#define HWDIM 56
#define IMG   (HWDIM * HWDIM)   // 3136
#define K_TOT (CIN * 9)         // 2304
#define NIMG  32
#define NPIX  (NIMG * IMG)      // 100352
#define BM    256
#define BN    256
#define NCHUNK 36                // 18 steps x 2 half-chunks of 64 ch

#define AS1CAST(p) ((const __attribute__((address_space(1))) unsigned int*)(uintptr_t)(p))
#define AS3CAST(p) ((__attribute__((address_space(3))) unsigned int*)(uintptr_t)(p))

__device__ __forceinline__ ushort_t f2bf(float f) {
    union { float f; uint_t u; } v; v.f = f;
    uint_t u = v.u;
    uint_t r = u + 0x7FFFu + ((u >> 16) & 1u);   // RNE
    return (ushort_t)(r >> 16);
}

// ---------------------------------------------------------------------------
// Ternarize: per-filter delta/alpha; signs as exact bf16 into wt2[o][kpos][c].
// Block 0 also zeroes the xt halo pad row (row NPIX).
// ---------------------------------------------------------------------------
__global__ __launch_bounds__(256) void ternarize_kernel(
        const float* __restrict__ w,
        ushort_t* __restrict__ wt2,
        float* __restrict__ alpha_out,
        ushort_t* __restrict__ xt_pad_row) {
    const int o = blockIdx.x;
    const int t = threadIdx.x;
    const int lane = t & 63;
    const int wv = t >> 6;
    const float* base = w + (size_t)o * K_TOT;

    if (o == 0 && t < 32) ((uint4*)xt_pad_row)[t] = (uint4){0u, 0u, 0u, 0u};

    float v[9];
#pragma unroll
    for (int i = 0; i < 9; ++i) v[i] = base[t + 256 * i];

    __shared__ float sred[8];

    float s = 0.f;
#pragma unroll
    for (int i = 0; i < 9; ++i) s += fabsf(v[i]);
#pragma unroll
    for (int off = 32; off > 0; off >>= 1) s += __shfl_down(s, off);
    if (lane == 0) sred[wv] = s;
    __syncthreads();
    if (t == 0) sred[0] = sred[0] + sred[1] + sred[2] + sred[3];
    __syncthreads();
    const float delta = (0.7f / (float)K_TOT) * sred[0];
    __syncthreads();

    float asum = 0.f, cnt = 0.f;
#pragma unroll
    for (int i = 0; i < 9; ++i) {
        float a = fabsf(v[i]);
        if (a > delta) { asum += a; cnt += 1.f; }
    }
#pragma unroll
    for (int off = 32; off > 0; off >>= 1) {
        asum += __shfl_down(asum, off);
        cnt  += __shfl_down(cnt, off);
    }
    if (lane == 0) { sred[wv] = asum; sred[4 + wv] = cnt; }
    __syncthreads();
    if (t == 0) {
        float at = sred[0] + sred[1] + sred[2] + sred[3];
        float ct = sred[4] + sred[5] + sred[6] + sred[7];
        alpha_out[o] = at / ct;
    }

#pragma unroll
    for (int i = 0; i < 9; ++i) {
        int idx = t + 256 * i;           // flat k = c*9 + r
        int c = idx / 9;
        int r = idx - c * 9;
        float x = v[i];
        ushort_t bits = 0;
        if (x > delta)       bits = 0x3F80u;
        else if (x < -delta) bits = 0xBF80u;
        wt2[(size_t)o * K_TOT + r * 256 + c] = bits;
    }
}

// ---------------------------------------------------------------------------
// Transpose + convert: x NCHW fp32 -> xt [pixel][channel] bf16.
// ---------------------------------------------------------------------------
__global__ __launch_bounds__(256) void transpose_kernel(
        const float* __restrict__ x, ushort_t* __restrict__ xt) {
    __shared__ float L[32][132];
    const int hw0 = blockIdx.x * 32;
    const int c0  = blockIdx.y * 128;
    const int n   = blockIdx.z;
    const int t = threadIdx.x;
    const int c_ = t >> 1;        // 0..127
    const int half = t & 1;

    const float* src = x + (size_t)(n * CIN + c0 + c_) * IMG + hw0 + half * 16;
    float4 v[4];
#pragma unroll
    for (int k = 0; k < 4; ++k) v[k] = *(const float4*)(src + k * 4);
#pragma unroll
    for (int k = 0; k < 4; ++k) {
        L[half * 16 + k * 4 + 0][c_] = v[k].x;
        L[half * 16 + k * 4 + 1][c_] = v[k].y;
        L[half * 16 + k * 4 + 2][c_] = v[k].z;
        L[half * 16 + k * 4 + 3][c_] = v[k].w;
    }
    __syncthreads();

    const int seg = t & 15;       // 8-channel segment
    const int hwb = t >> 4;       // 0..15
#pragma unroll
    for (int j = 0; j < 2; ++j) {
        const int hwl = hwb + j * 16;
        const float2* row = (const float2*)&L[hwl][seg * 8];
        uint_t pk[4];
#pragma unroll
        for (int q = 0; q < 4; ++q) {
            float2 f = row[q];
            pk[q] = (uint_t)f2bf(f.x) | ((uint_t)f2bf(f.y) << 16);
        }
        *(uint4*)&xt[(size_t)(n * IMG + hw0 + hwl) * CIN + c0 + seg * 8] =
            (uint4){pk[0], pk[1], pk[2], pk[3]};
    }
}

// ---------------------------------------------------------------------------
// Implicit-GEMM conv, 256x256 tile, 8 waves (2M x 4N, wave tile 128x64).
// m201-style 4-phase fine interleave per 64-ch chunk (slot P = c&1):
//   phase q (q=0..3):
//     reads (slot P): A-pair q (4 ds_read_b128); q==0: + X-all (8)
//     q==0: STAGE chunk c+1 -> slot 1-P (8 global_load_lds)
//     q==3: vmcnt(0)            // c+1's stages (issued q0, ~3 phases back) landed
//     barrier
//     setprio(1); 16 MFMA (m-pair q x 4 nt x 2 kh); setprio(0)
//       (compiler inserts fine-grained lgkmcnt for the frag loads)
//     barrier
// WAR: stage(c+1 -> 1-P) issues after chunk c-1's final barrier; all slot-(1-P)
// reads completed before their consuming MFMAs in c-1 -> safe by construction.
// RAW: vmcnt(0)@q3 + barrier precede the next chunk's reads.
// Regs: 128 acc + X 32 + A-pair 16 + addr ~54 = ~230 <= 256 (no spill, no
// sched_barrier needed: barriers fence ds_read motion across phases).
// Ledger: <=8 outstanding; chunk 35 stages/waits nothing; closes at 0.
// ---------------------------------------------------------------------------
__global__ __launch_bounds__(512, 1) void tern_conv_kernel(
        const ushort_t* __restrict__ xt,    // [(NPIX+1)][256]
        const ushort_t* __restrict__ wt2,   // [256 o][9][256 c]
        const float* __restrict__ alpha,
        const float* __restrict__ bias,
        float* __restrict__ out) {
    __shared__ __align__(16) ushort_t As[2][BM * 64];   // 2 x 32 KB
    __shared__ __align__(16) ushort_t Xs[2][BN * 64];   // 2 x 32 KB

    const int tid = threadIdx.x;          // 0..511
    const int wv = tid >> 6;              // 0..7
    const int l = tid & 63;
    const int p0 = blockIdx.x * BN;

    const int rthr = tid >> 3;                 // 0..63: staging row within a round
    const int g = (l & 7) ^ ((l >> 3) & 7);    // swizzled source 8-ch segment

    // per-thread staging sources: 4 row-slots, stride 64
    const ushort_t* abase[4];
    int ximg[4], xh[4], xw[4];
#pragma unroll
    for (int i = 0; i < 4; ++i) {
        abase[i] = wt2 + (size_t)(i * 64 + rthr) * K_TOT + g * 8;
        int p = p0 + i * 64 + rthr;
        int n_img = p / IMG;
        int hw_ = p - n_img * IMG;
        xh[i] = hw_ / HWDIM;
        xw[i] = hw_ - xh[i] * HWDIM;
        ximg[i] = n_img * IMG;
    }

    // wave-uniform LDS staging destinations (element offsets); lane adds l*16B
    int doff[4];
#pragma unroll
    for (int i = 0; i < 4; ++i) doff[i] = (i * 64 + wv * 8) * 64;

    // fragment-read geometry: wave tile 128x64 at (wm, wn)
    const int qd = l >> 4, ln = l & 15;
    const int wm = (wv >> 2) * 128;            // 0 or 128
    const int wn = (wv & 3) * 64;              // 0,64,128,192
    const int so0 = (qd ^ (ln & 7)) * 8;       // de-swizzle; k-half 1 is so0^32
    int arow[8], xrow[4];
#pragma unroll
    for (int i = 0; i < 8; ++i) arow[i] = (wm + i * 16 + ln) * 64;
#pragma unroll
    for (int j = 0; j < 4; ++j) xrow[j] = (wn + j * 16 + ln) * 64;

    f32x4 acc[8][4];
#pragma unroll
    for (int i = 0; i < 8; ++i)
#pragma unroll
        for (int j = 0; j < 4; ++j)
            acc[i][j] = (f32x4){0.f, 0.f, 0.f, 0.f};

    bf16x8 xf[8];   // X frags [nt*2+kh], live whole chunk (32 VGPR)
    bf16x8 af[4];   // A-pair frags [mloc*2+kh], live one phase (16 VGPR)

#define STAGE_CHUNK(c, SLOT) do {                                               \
    const int st_ = (c) >> 1, hs_ = (c) & 1;                                    \
    const int c0_ = (st_ >= 9) ? 128 : 0;                                       \
    const int kp_ = st_ - ((st_ >= 9) ? 9 : 0);                                 \
    const int dh_ = kp_ / 3 - 1;                                                \
    const int dw_ = kp_ - (dh_ + 1) * 3 - 1;                                    \
    const int aoff_ = kp_ * 256 + c0_ + hs_ * 64;                               \
    _Pragma("unroll")                                                           \
    for (int i = 0; i < 4; ++i)                                                 \
        __builtin_amdgcn_global_load_lds(AS1CAST(abase[i] + aoff_),             \
                                         AS3CAST(&As[SLOT][doff[i]]), 16, 0, 0);\
    _Pragma("unroll")                                                           \
    for (int i = 0; i < 4; ++i) {                                               \
        int h2_ = xh[i] + dh_, w2_ = xw[i] + dw_;                               \
        int row_ = ((unsigned)h2_ < (unsigned)HWDIM &&                          \
                    (unsigned)w2_ < (unsigned)HWDIM)                            \
                       ? (ximg[i] + h2_ * HWDIM + w2_) : NPIX;                  \
        __builtin_amdgcn_global_load_lds(                                       \
            AS1CAST(xt + (size_t)row_ * CIN + c0_ + hs_ * 64 + g * 8),          \
            AS3CAST(&Xs[SLOT][doff[i]]), 16, 0, 0);                             \
    }                                                                           \
} while (0)

#define READ_X(P) do {                                                          \
    _Pragma("unroll")                                                           \
    for (int n = 0; n < 4; ++n) {                                               \
        xf[n * 2 + 0] = *(const bf16x8*)&Xs[P][xrow[n] + so0];                  \
        xf[n * 2 + 1] = *(const bf16x8*)&Xs[P][xrow[n] + (so0 ^ 32)];           \
    }                                                                           \
} while (0)

#define READ_A(P, q) do {                                                       \
    af[0] = *(const bf16x8*)&As[P][arow[2 * (q) + 0] + so0];                    \
    af[1] = *(const bf16x8*)&As[P][arow[2 * (q) + 0] + (so0 ^ 32)];             \
    af[2] = *(const bf16x8*)&As[P][arow[2 * (q) + 1] + so0];                    \
    af[3] = *(const bf16x8*)&As[P][arow[2 * (q) + 1] + (so0 ^ 32)];             \
} while (0)

#define MFMA_PAIR(q) do {                                                       \
    __builtin_amdgcn_s_setprio(1);                                              \
    _Pragma("unroll")                                                           \
    for (int mloc = 0; mloc < 2; ++mloc)                                        \
        _Pragma("unroll")                                                       \
        for (int n = 0; n < 4; ++n) {                                           \
            acc[2 * (q) + mloc][n] = __builtin_amdgcn_mfma_f32_16x16x32_bf16(   \
                af[mloc * 2 + 0], xf[n * 2 + 0], acc[2 * (q) + mloc][n], 0, 0, 0);\
            acc[2 * (q) + mloc][n] = __builtin_amdgcn_mfma_f32_16x16x32_bf16(   \
                af[mloc * 2 + 1], xf[n * 2 + 1], acc[2 * (q) + mloc][n], 0, 0, 0);\
        }                                                                       \
    __builtin_amdgcn_s_setprio(0);                                              \
} while (0)

#define BAR() do {                                                              \
    __builtin_amdgcn_s_barrier();                                               \
    asm volatile("" ::: "memory");                                              \
} while (0)

#define CHUNK(kc, P, DO_NEXT) do {                                              \
    /* phase 0 */                                                               \
    READ_X(P); READ_A(P, 0);                                                    \
    if (DO_NEXT) STAGE_CHUNK((kc) + 1, 1 - (P));                                \
    BAR();                                                                      \
    MFMA_PAIR(0);                                                               \
    BAR();                                                                      \
    /* phase 1 */                                                               \
    READ_A(P, 1);                                                               \
    BAR();                                                                      \
    MFMA_PAIR(1);                                                               \
    BAR();                                                                      \
    /* phase 2 */                                                               \
    READ_A(P, 2);                                                               \
    BAR();                                                                      \
    MFMA_PAIR(2);                                                               \
    BAR();                                                                      \
    /* phase 3 */                                                               \
    READ_A(P, 3);                                                               \
    if (DO_NEXT) asm volatile("s_waitcnt vmcnt(0)" ::: "memory");               \
    BAR();                                                                      \
    MFMA_PAIR(3);                                                               \
    BAR();                                                                      \
} while (0)

    // ---- prologue: stage chunk 0 -> slot 0; wait; sync
    STAGE_CHUNK(0, 0);
    asm volatile("s_waitcnt vmcnt(0)" ::: "memory");
    BAR();

    // ---- chunks 0..33 in parity pairs, then 34 (stages 35), then 35 (drains)
#pragma unroll 1
    for (int c = 0; c < 34; c += 2) {
        CHUNK(c, 0, 1);
        CHUNK(c + 1, 1, 1);
    }
    CHUNK(34, 0, 1);
    CHUNK(35, 1, 0);

#undef CHUNK
#undef BAR
#undef MFMA_PAIR
#undef READ_A
#undef READ_X
#undef STAGE_CHUNK

    // epilogue: out[n][o][h][w] = alpha[o]*acc + bias[o]
#pragma unroll
    for (int im = 0; im < 8; ++im) {
        const int orow = wm + im * 16 + qd * 4;
        const f32x4 al = *(const f32x4*)&alpha[orow];
        const f32x4 bi = *(const f32x4*)&bias[orow];
#pragma unroll
        for (int in2 = 0; in2 < 4; ++in2) {
            const int pc = p0 + wn + in2 * 16 + ln;
            const int ni = pc / IMG;
            const int hwc = pc - ni * IMG;
            const size_t obase = (size_t)ni * COUT * IMG + hwc;
#pragma unroll
            for (int rr = 0; rr < 4; ++rr)
                out[obase + (size_t)(orow + rr) * IMG] = al[rr] * acc[im][in2][rr] + bi[rr];
        }
    }
}

extern "C" void kernel_launch(void* const* d_in, const int* in_sizes, int n_in,
                              void* d_out, int out_size, void* d_ws, size_t ws_size,
                              hipStream_t stream) {
    const float* x      = (const float*)d_in[0];
    const float* weight = (const float*)d_in[1];
    const float* bias   = (const float*)d_in[2];
    float* out = (float*)d_out;

    // workspace: xt (NPIX+1)*256 bf16 (last row = zero halo), wt2, alpha
    ushort_t* xt     = (ushort_t*)d_ws;
    ushort_t* wt2    = (ushort_t*)((char*)d_ws + (size_t)(NPIX + 1) * CIN * sizeof(ushort_t));
    float*    alphav = (float*)((char*)wt2 + (size_t)COUT * K_TOT * sizeof(ushort_t));

    ternarize_kernel<<<COUT, 256, 0, stream>>>(weight, wt2, alphav,
                                               xt + (size_t)NPIX * CIN);

    dim3 tg(IMG / 32, CIN / 128, NIMG);  // 98 x 2 x 32
    transpose_kernel<<<tg, 256, 0, stream>>>(x, xt);

    const int n_blocks = NPIX / BN;      // 392
    tern_conv_kernel<<<n_blocks, 512, 0, stream>>>(xt, wt2, alphav, bias, out);
}

// Round 10
// 302.795 us; speedup vs baseline: 1.7712x; 1.0415x over previous
//
#include <hip/hip_runtime.h>
#include <hip/hip_bf16.h>
#include <stdint.h>

typedef short bf16x8 __attribute__((ext_vector_type(8)));
typedef float f32x4 __attribute__((ext_vector_type(4)));
typedef unsigned short ushort_t;
typedef unsigned int uint_t;

#define CIN   256
#define COUT  256
#define HWDIM 56
#define IMG   (HWDIM * HWDIM)   // 3136
#define K_TOT (CIN * 9)         // 2304
#define NIMG  32
#define NPIX  (NIMG * IMG)      // 100352
#define BM    256
#define BN    256
#define NCHUNK 36                // 18 steps x 2 half-chunks of 64 ch

#define AS1CAST(p) ((const __attribute__((address_space(1))) unsigned int*)(uintptr_t)(p))
#define AS3CAST(p) ((__attribute__((address_space(3))) unsigned int*)(uintptr_t)(p))

__device__ __forceinline__ ushort_t f2bf(float f) {
    union { float f; uint_t u; } v; v.f = f;
    uint_t u = v.u;
    uint_t r = u + 0x7FFFu + ((u >> 16) & 1u);   // RNE
    return (ushort_t)(r >> 16);
}

// ---------------------------------------------------------------------------
// Ternarize: per-filter delta/alpha; signs as exact bf16 into wt2[o][kpos][c].
// Block 0 also zeroes the xt halo pad row (row NPIX).
// ---------------------------------------------------------------------------
__global__ __launch_bounds__(256) void ternarize_kernel(
        const float* __restrict__ w,
        ushort_t* __restrict__ wt2,
        float* __restrict__ alpha_out,
        ushort_t* __restrict__ xt_pad_row) {
    const int o = blockIdx.x;
    const int t = threadIdx.x;
    const int lane = t & 63;
    const int wv = t >> 6;
    const float* base = w + (size_t)o * K_TOT;

    if (o == 0 && t < 32) ((uint4*)xt_pad_row)[t] = (uint4){0u, 0u, 0u, 0u};

    float v[9];
#pragma unroll
    for (int i = 0; i < 9; ++i) v[i] = base[t + 256 * i];

    __shared__ float sred[8];

    float s = 0.f;
#pragma unroll
    for (int i = 0; i < 9; ++i) s += fabsf(v[i]);
#pragma unroll
    for (int off = 32; off > 0; off >>= 1) s += __shfl_down(s, off);
    if (lane == 0) sred[wv] = s;
    __syncthreads();
    if (t == 0) sred[0] = sred[0] + sred[1] + sred[2] + sred[3];
    __syncthreads();
    const float delta = (0.7f / (float)K_TOT) * sred[0];
    __syncthreads();

    float asum = 0.f, cnt = 0.f;
#pragma unroll
    for (int i = 0; i < 9; ++i) {
        float a = fabsf(v[i]);
        if (a > delta) { asum += a; cnt += 1.f; }
    }
#pragma unroll
    for (int off = 32; off > 0; off >>= 1) {
        asum += __shfl_down(asum, off);
        cnt  += __shfl_down(cnt, off);
    }
    if (lane == 0) { sred[wv] = asum; sred[4 + wv] = cnt; }
    __syncthreads();
    if (t == 0) {
        float at = sred[0] + sred[1] + sred[2] + sred[3];
        float ct = sred[4] + sred[5] + sred[6] + sred[7];
        alpha_out[o] = at / ct;
    }

#pragma unroll
    for (int i = 0; i < 9; ++i) {
        int idx = t + 256 * i;           // flat k = c*9 + r
        int c = idx / 9;
        int r = idx - c * 9;
        float x = v[i];
        ushort_t bits = 0;
        if (x > delta)       bits = 0x3F80u;
        else if (x < -delta) bits = 0xBF80u;
        wt2[(size_t)o * K_TOT + r * 256 + c] = bits;
    }
}

// ---------------------------------------------------------------------------
// Transpose + convert: x NCHW fp32 -> xt [pixel][channel] bf16.
// ---------------------------------------------------------------------------
__global__ __launch_bounds__(256) void transpose_kernel(
        const float* __restrict__ x, ushort_t* __restrict__ xt) {
    __shared__ float L[32][132];
    const int hw0 = blockIdx.x * 32;
    const int c0  = blockIdx.y * 128;
    const int n   = blockIdx.z;
    const int t = threadIdx.x;
    const int c_ = t >> 1;        // 0..127
    const int half = t & 1;

    const float* src = x + (size_t)(n * CIN + c0 + c_) * IMG + hw0 + half * 16;
    float4 v[4];
#pragma unroll
    for (int k = 0; k < 4; ++k) v[k] = *(const float4*)(src + k * 4);
#pragma unroll
    for (int k = 0; k < 4; ++k) {
        L[half * 16 + k * 4 + 0][c_] = v[k].x;
        L[half * 16 + k * 4 + 1][c_] = v[k].y;
        L[half * 16 + k * 4 + 2][c_] = v[k].z;
        L[half * 16 + k * 4 + 3][c_] = v[k].w;
    }
    __syncthreads();

    const int seg = t & 15;       // 8-channel segment
    const int hwb = t >> 4;       // 0..15
#pragma unroll
    for (int j = 0; j < 2; ++j) {
        const int hwl = hwb + j * 16;
        const float2* row = (const float2*)&L[hwl][seg * 8];
        uint_t pk[4];
#pragma unroll
        for (int q = 0; q < 4; ++q) {
            float2 f = row[q];
            pk[q] = (uint_t)f2bf(f.x) | ((uint_t)f2bf(f.y) << 16);
        }
        *(uint4*)&xt[(size_t)(n * IMG + hw0 + hwl) * CIN + c0 + seg * 8] =
            (uint4){pk[0], pk[1], pk[2], pk[3]};
    }
}

// ---------------------------------------------------------------------------
// Implicit-GEMM conv, 256x256 tile, 8 waves (2M x 4N, wave tile 128x64).
// 36 chunks of {one kpos x 64 ch}; 2 LDS slots by chunk parity; 128 KB LDS.
// TWO barriers per chunk (R9's 8 were lockstep overkill -> 48% idle):
//   [entry: boundary barrier passed; slot P certified]
//   half A: READ_X (8) + READ_A rows0-3 (8) + STAGE(c+1 -> 1-P)
//           + 32 MFMA (m0..3) -- free-flowing, compiler interleaves,
//           waves drift; reads drain under MFMAs via fine lgkmcnt
//   BAR      (anti-hoist fence: caps co-live frags at xf32+af32=64 VGPR)
//   half B: READ_A rows4-7 (8) + 32 MFMA (m4..7)
//   lgkm(0)  // WAR cert: my slot-P reads retired
//   vmcnt(0) // RAW cert: my 8 loads for chunk c+1 landed (~1 chunk in flight)
//   BAR      (chunk boundary: certificates globalized)
// Intra-chunk hazards: none (reads slot P, stage writes slot 1-P).
// Regs: 128 acc + 64 frags + ~50 addr = ~242 <= 256, no sched_barrier needed.
// Ledger: 8 outstanding per chunk, drained at boundary; chunk 35 stages none.
// ---------------------------------------------------------------------------
__global__ __launch_bounds__(512, 1) void tern_conv_kernel(
        const ushort_t* __restrict__ xt,    // [(NPIX+1)][256]
        const ushort_t* __restrict__ wt2,   // [256 o][9][256 c]
        const float* __restrict__ alpha,
        const float* __restrict__ bias,
        float* __restrict__ out) {
    __shared__ __align__(16) ushort_t As[2][BM * 64];   // 2 x 32 KB
    __shared__ __align__(16) ushort_t Xs[2][BN * 64];   // 2 x 32 KB

    const int tid = threadIdx.x;          // 0..511
    const int wv = tid >> 6;              // 0..7
    const int l = tid & 63;
    const int p0 = blockIdx.x * BN;

    const int rthr = tid >> 3;                 // 0..63: staging row within a round
    const int g = (l & 7) ^ ((l >> 3) & 7);    // swizzled source 8-ch segment

    // per-thread staging sources: 4 row-slots, stride 64
    const ushort_t* abase[4];
    int ximg[4], xh[4], xw[4];
#pragma unroll
    for (int i = 0; i < 4; ++i) {
        abase[i] = wt2 + (size_t)(i * 64 + rthr) * K_TOT + g * 8;
        int p = p0 + i * 64 + rthr;
        int n_img = p / IMG;
        int hw_ = p - n_img * IMG;
        xh[i] = hw_ / HWDIM;
        xw[i] = hw_ - xh[i] * HWDIM;
        ximg[i] = n_img * IMG;
    }

    // wave-uniform LDS staging destinations (element offsets); lane adds l*16B
    int doff[4];
#pragma unroll
    for (int i = 0; i < 4; ++i) doff[i] = (i * 64 + wv * 8) * 64;

    // fragment-read geometry: wave tile 128x64 at (wm, wn)
    const int qd = l >> 4, ln = l & 15;
    const int wm = (wv >> 2) * 128;            // 0 or 128
    const int wn = (wv & 3) * 64;              // 0,64,128,192
    const int so0 = (qd ^ (ln & 7)) * 8;       // de-swizzle; k-half 1 is so0^32
    int arow[8], xrow[4];
#pragma unroll
    for (int i = 0; i < 8; ++i) arow[i] = (wm + i * 16 + ln) * 64;
#pragma unroll
    for (int j = 0; j < 4; ++j) xrow[j] = (wn + j * 16 + ln) * 64;

    f32x4 acc[8][4];
#pragma unroll
    for (int i = 0; i < 8; ++i)
#pragma unroll
        for (int j = 0; j < 4; ++j)
            acc[i][j] = (f32x4){0.f, 0.f, 0.f, 0.f};

    bf16x8 xf[8];   // X frags [nt*2+kh], live whole chunk (32 VGPR)
    bf16x8 af[8];   // A frags for 4 m-rows [(row&3)*2+kh], one half (32 VGPR)

#define STAGE_CHUNK(c, SLOT) do {                                               \
    const int st_ = (c) >> 1, hs_ = (c) & 1;                                    \
    const int c0_ = (st_ >= 9) ? 128 : 0;                                       \
    const int kp_ = st_ - ((st_ >= 9) ? 9 : 0);                                 \
    const int dh_ = kp_ / 3 - 1;                                                \
    const int dw_ = kp_ - (dh_ + 1) * 3 - 1;                                    \
    const int aoff_ = kp_ * 256 + c0_ + hs_ * 64;                               \
    _Pragma("unroll")                                                           \
    for (int i = 0; i < 4; ++i)                                                 \
        __builtin_amdgcn_global_load_lds(AS1CAST(abase[i] + aoff_),             \
                                         AS3CAST(&As[SLOT][doff[i]]), 16, 0, 0);\
    _Pragma("unroll")                                                           \
    for (int i = 0; i < 4; ++i) {                                               \
        int h2_ = xh[i] + dh_, w2_ = xw[i] + dw_;                               \
        int row_ = ((unsigned)h2_ < (unsigned)HWDIM &&                          \
                    (unsigned)w2_ < (unsigned)HWDIM)                            \
                       ? (ximg[i] + h2_ * HWDIM + w2_) : NPIX;                  \
        __builtin_amdgcn_global_load_lds(                                       \
            AS1CAST(xt + (size_t)row_ * CIN + c0_ + hs_ * 64 + g * 8),          \
            AS3CAST(&Xs[SLOT][doff[i]]), 16, 0, 0);                             \
    }                                                                           \
} while (0)

#define READ_X(P) do {                                                          \
    _Pragma("unroll")                                                           \
    for (int n = 0; n < 4; ++n) {                                               \
        xf[n * 2 + 0] = *(const bf16x8*)&Xs[P][xrow[n] + so0];                  \
        xf[n * 2 + 1] = *(const bf16x8*)&Xs[P][xrow[n] + (so0 ^ 32)];           \
    }                                                                           \
} while (0)

// read A rows 4h..4h+3 into af[0..7]
#define READ_A4(P, h) do {                                                      \
    _Pragma("unroll")                                                           \
    for (int r = 0; r < 4; ++r) {                                               \
        af[r * 2 + 0] = *(const bf16x8*)&As[P][arow[4 * (h) + r] + so0];        \
        af[r * 2 + 1] = *(const bf16x8*)&As[P][arow[4 * (h) + r] + (so0 ^ 32)]; \
    }                                                                           \
} while (0)

// 32 MFMA: m-rows 4h..4h+3 x 4 n x 2 kh
#define MFMA_HALF(h) do {                                                       \
    __builtin_amdgcn_s_setprio(1);                                              \
    _Pragma("unroll")                                                           \
    for (int r = 0; r < 4; ++r)                                                 \
        _Pragma("unroll")                                                       \
        for (int n = 0; n < 4; ++n) {                                           \
            acc[4 * (h) + r][n] = __builtin_amdgcn_mfma_f32_16x16x32_bf16(      \
                af[r * 2 + 0], xf[n * 2 + 0], acc[4 * (h) + r][n], 0, 0, 0);    \
            acc[4 * (h) + r][n] = __builtin_amdgcn_mfma_f32_16x16x32_bf16(      \
                af[r * 2 + 1], xf[n * 2 + 1], acc[4 * (h) + r][n], 0, 0, 0);    \
        }                                                                       \
    __builtin_amdgcn_s_setprio(0);                                              \
} while (0)

#define BAR() do {                                                              \
    __builtin_amdgcn_s_barrier();                                               \
    asm volatile("" ::: "memory");                                              \
} while (0)

#define CHUNK(kc, P, DO_NEXT) do {                                              \
    /* half A: m-rows 0..3; issue next-chunk stage early (T14) */               \
    READ_X(P);                                                                  \
    READ_A4(P, 0);                                                              \
    if (DO_NEXT) STAGE_CHUNK((kc) + 1, 1 - (P));                                \
    MFMA_HALF(0);                                                               \
    BAR();   /* anti-hoist fence: half-B reads may not move up (reg cap) */     \
    /* half B: m-rows 4..7 */                                                   \
    READ_A4(P, 1);                                                              \
    MFMA_HALF(1);                                                               \
    asm volatile("s_waitcnt lgkmcnt(0)" ::: "memory");  /* WAR cert */          \
    if (DO_NEXT) asm volatile("s_waitcnt vmcnt(0)" ::: "memory"); /* RAW */     \
    BAR();   /* chunk boundary: certificates globalized */                      \
} while (0)

    // ---- prologue: stage chunk 0 -> slot 0; wait; sync
    STAGE_CHUNK(0, 0);
    asm volatile("s_waitcnt vmcnt(0)" ::: "memory");
    BAR();

    // ---- chunks 0..33 in parity pairs, then 34 (stages 35), then 35 (drains)
#pragma unroll 1
    for (int c = 0; c < 34; c += 2) {
        CHUNK(c, 0, 1);
        CHUNK(c + 1, 1, 1);
    }
    CHUNK(34, 0, 1);
    CHUNK(35, 1, 0);

#undef CHUNK
#undef BAR
#undef MFMA_HALF
#undef READ_A4
#undef READ_X
#undef STAGE_CHUNK

    // epilogue: out[n][o][h][w] = alpha[o]*acc + bias[o]
#pragma unroll
    for (int im = 0; im < 8; ++im) {
        const int orow = wm + im * 16 + qd * 4;
        const f32x4 al = *(const f32x4*)&alpha[orow];
        const f32x4 bi = *(const f32x4*)&bias[orow];
#pragma unroll
        for (int in2 = 0; in2 < 4; ++in2) {
            const int pc = p0 + wn + in2 * 16 + ln;
            const int ni = pc / IMG;
            const int hwc = pc - ni * IMG;
            const size_t obase = (size_t)ni * COUT * IMG + hwc;
#pragma unroll
            for (int rr = 0; rr < 4; ++rr)
                out[obase + (size_t)(orow + rr) * IMG] = al[rr] * acc[im][in2][rr] + bi[rr];
        }
    }
}

extern "C" void kernel_launch(void* const* d_in, const int* in_sizes, int n_in,
                              void* d_out, int out_size, void* d_ws, size_t ws_size,
                              hipStream_t stream) {
    const float* x      = (const float*)d_in[0];
    const float* weight = (const float*)d_in[1];
    const float* bias   = (const float*)d_in[2];
    float* out = (float*)d_out;

    // workspace: xt (NPIX+1)*256 bf16 (last row = zero halo), wt2, alpha
    ushort_t* xt     = (ushort_t*)d_ws;
    ushort_t* wt2    = (ushort_t*)((char*)d_ws + (size_t)(NPIX + 1) * CIN * sizeof(ushort_t));
    float*    alphav = (float*)((char*)wt2 + (size_t)COUT * K_TOT * sizeof(ushort_t));

    ternarize_kernel<<<COUT, 256, 0, stream>>>(weight, wt2, alphav,
                                               xt + (size_t)NPIX * CIN);

    dim3 tg(IMG / 32, CIN / 128, NIMG);  // 98 x 2 x 32
    transpose_kernel<<<tg, 256, 0, stream>>>(x, xt);

    const int n_blocks = NPIX / BN;      // 392
    tern_conv_kernel<<<n_blocks, 512, 0, stream>>>(xt, wt2, alphav, bias, out);
}

// Round 11
// 300.379 us; speedup vs baseline: 1.7854x; 1.0080x over previous
//
#include <hip/hip_runtime.h>
#include <hip/hip_bf16.h>
#include <stdint.h>

typedef short bf16x8 __attribute__((ext_vector_type(8)));
typedef float f32x4 __attribute__((ext_vector_type(4)));
typedef unsigned short ushort_t;
typedef unsigned int uint_t;

#define CIN   256
#define COUT  256
#define HWDIM 56
#define IMG   (HWDIM * HWDIM)   // 3136
#define K_TOT (CIN * 9)         // 2304
#define NIMG  32
#define NPIX  (NIMG * IMG)      // 100352
#define BM    256
#define BN    256
#define NCHUNK 36                // 18 steps x 2 half-chunks of 64 ch

#define AS1CAST(p) ((const __attribute__((address_space(1))) unsigned int*)(uintptr_t)(p))
#define AS3CAST(p) ((__attribute__((address_space(3))) unsigned int*)(uintptr_t)(p))

__device__ __forceinline__ ushort_t f2bf(float f) {
    union { float f; uint_t u; } v; v.f = f;
    uint_t u = v.u;
    uint_t r = u + 0x7FFFu + ((u >> 16) & 1u);   // RNE
    return (ushort_t)(r >> 16);
}

// ---------------------------------------------------------------------------
// Ternarize: per-filter delta/alpha; signs as exact bf16 into wt2[o][kpos][c].
// Block 0 also zeroes the xt halo pad row (row NPIX).
// ---------------------------------------------------------------------------
__global__ __launch_bounds__(256) void ternarize_kernel(
        const float* __restrict__ w,
        ushort_t* __restrict__ wt2,
        float* __restrict__ alpha_out,
        ushort_t* __restrict__ xt_pad_row) {
    const int o = blockIdx.x;
    const int t = threadIdx.x;
    const int lane = t & 63;
    const int wv = t >> 6;
    const float* base = w + (size_t)o * K_TOT;

    if (o == 0 && t < 32) ((uint4*)xt_pad_row)[t] = (uint4){0u, 0u, 0u, 0u};

    float v[9];
#pragma unroll
    for (int i = 0; i < 9; ++i) v[i] = base[t + 256 * i];

    __shared__ float sred[8];

    float s = 0.f;
#pragma unroll
    for (int i = 0; i < 9; ++i) s += fabsf(v[i]);
#pragma unroll
    for (int off = 32; off > 0; off >>= 1) s += __shfl_down(s, off);
    if (lane == 0) sred[wv] = s;
    __syncthreads();
    if (t == 0) sred[0] = sred[0] + sred[1] + sred[2] + sred[3];
    __syncthreads();
    const float delta = (0.7f / (float)K_TOT) * sred[0];
    __syncthreads();

    float asum = 0.f, cnt = 0.f;
#pragma unroll
    for (int i = 0; i < 9; ++i) {
        float a = fabsf(v[i]);
        if (a > delta) { asum += a; cnt += 1.f; }
    }
#pragma unroll
    for (int off = 32; off > 0; off >>= 1) {
        asum += __shfl_down(asum, off);
        cnt  += __shfl_down(cnt, off);
    }
    if (lane == 0) { sred[wv] = asum; sred[4 + wv] = cnt; }
    __syncthreads();
    if (t == 0) {
        float at = sred[0] + sred[1] + sred[2] + sred[3];
        float ct = sred[4] + sred[5] + sred[6] + sred[7];
        alpha_out[o] = at / ct;
    }

#pragma unroll
    for (int i = 0; i < 9; ++i) {
        int idx = t + 256 * i;           // flat k = c*9 + r
        int c = idx / 9;
        int r = idx - c * 9;
        float x = v[i];
        ushort_t bits = 0;
        if (x > delta)       bits = 0x3F80u;
        else if (x < -delta) bits = 0xBF80u;
        wt2[(size_t)o * K_TOT + r * 256 + c] = bits;
    }
}

// ---------------------------------------------------------------------------
// Transpose + convert: x NCHW fp32 -> xt [pixel][channel] bf16.
// ---------------------------------------------------------------------------
__global__ __launch_bounds__(256) void transpose_kernel(
        const float* __restrict__ x, ushort_t* __restrict__ xt) {
    __shared__ float L[32][132];
    const int hw0 = blockIdx.x * 32;
    const int c0  = blockIdx.y * 128;
    const int n   = blockIdx.z;
    const int t = threadIdx.x;
    const int c_ = t >> 1;        // 0..127
    const int half = t & 1;

    const float* src = x + (size_t)(n * CIN + c0 + c_) * IMG + hw0 + half * 16;
    float4 v[4];
#pragma unroll
    for (int k = 0; k < 4; ++k) v[k] = *(const float4*)(src + k * 4);
#pragma unroll
    for (int k = 0; k < 4; ++k) {
        L[half * 16 + k * 4 + 0][c_] = v[k].x;
        L[half * 16 + k * 4 + 1][c_] = v[k].y;
        L[half * 16 + k * 4 + 2][c_] = v[k].z;
        L[half * 16 + k * 4 + 3][c_] = v[k].w;
    }
    __syncthreads();

    const int seg = t & 15;       // 8-channel segment
    const int hwb = t >> 4;       // 0..15
#pragma unroll
    for (int j = 0; j < 2; ++j) {
        const int hwl = hwb + j * 16;
        const float2* row = (const float2*)&L[hwl][seg * 8];
        uint_t pk[4];
#pragma unroll
        for (int q = 0; q < 4; ++q) {
            float2 f = row[q];
            pk[q] = (uint_t)f2bf(f.x) | ((uint_t)f2bf(f.y) << 16);
        }
        *(uint4*)&xt[(size_t)(n * IMG + hw0 + hwl) * CIN + c0 + seg * 8] =
            (uint4){pk[0], pk[1], pk[2], pk[3]};
    }
}

// ---------------------------------------------------------------------------
// Implicit-GEMM conv, 256x256 tile, 8 waves (2M x 4N, wave tile 128x64).
// 36 chunks of {one kpos x 64 ch}; 2 LDS slots by chunk parity; 128 KB LDS.
// ONE barrier per chunk + intra-chunk register pipeline over A-row-pairs.
// R10's read-region/MFMA-region lockstep measured 4520 cy/chunk = LDS(2000)
// + MFMA(2483) SERIAL; this overlaps them within each wave:
//   READ_X (8 ds) ; READ pair0 -> afa ; STAGE(c+1 -> 1-P)
//   READ pair1 -> afb ; 16 MFMA on afa     // reads in flight under MFMAs
//   READ pair2 -> afa ; 16 MFMA on afb
//   READ pair3 -> afb ; 16 MFMA on afa
//   16 MFMA on afb
//   lgkm(0)  // WAR cert (free: last MFMA already waited its frags)
//   vmcnt(0) // RAW cert (free: stage issued ~2500 cy earlier)
//   BAR      // boundary: certificates globalized
// Co-live regs: 128 acc + 32 xf + 2x16 af + ~45 addr = ~237 <= 256, bounded
// by static double-buffer naming (no sched_barrier). Certificates identical
// to the verified R10 ledger (stage distance 1, slot parity alternates).
// ---------------------------------------------------------------------------
__global__ __launch_bounds__(512, 1) void tern_conv_kernel(
        const ushort_t* __restrict__ xt,    // [(NPIX+1)][256]
        const ushort_t* __restrict__ wt2,   // [256 o][9][256 c]
        const float* __restrict__ alpha,
        const float* __restrict__ bias,
        float* __restrict__ out) {
    __shared__ __align__(16) ushort_t As[2][BM * 64];   // 2 x 32 KB
    __shared__ __align__(16) ushort_t Xs[2][BN * 64];   // 2 x 32 KB

    const int tid = threadIdx.x;          // 0..511
    const int wv = tid >> 6;              // 0..7
    const int l = tid & 63;
    const int p0 = blockIdx.x * BN;

    const int rthr = tid >> 3;                 // 0..63: staging row within a round
    const int g = (l & 7) ^ ((l >> 3) & 7);    // swizzled source 8-ch segment

    // per-thread staging sources: 4 row-slots, stride 64
    const ushort_t* abase[4];
    int ximg[4], xh[4], xw[4];
#pragma unroll
    for (int i = 0; i < 4; ++i) {
        abase[i] = wt2 + (size_t)(i * 64 + rthr) * K_TOT + g * 8;
        int p = p0 + i * 64 + rthr;
        int n_img = p / IMG;
        int hw_ = p - n_img * IMG;
        xh[i] = hw_ / HWDIM;
        xw[i] = hw_ - xh[i] * HWDIM;
        ximg[i] = n_img * IMG;
    }

    // wave-uniform LDS staging destinations (element offsets); lane adds l*16B
    int doff[4];
#pragma unroll
    for (int i = 0; i < 4; ++i) doff[i] = (i * 64 + wv * 8) * 64;

    // fragment-read geometry: wave tile 128x64 at (wm, wn)
    const int qd = l >> 4, ln = l & 15;
    const int wm = (wv >> 2) * 128;            // 0 or 128
    const int wn = (wv & 3) * 64;              // 0,64,128,192
    const int so0 = (qd ^ (ln & 7)) * 8;       // de-swizzle; k-half 1 is so0^32
    int arow[8], xrow[4];
#pragma unroll
    for (int i = 0; i < 8; ++i) arow[i] = (wm + i * 16 + ln) * 64;
#pragma unroll
    for (int j = 0; j < 4; ++j) xrow[j] = (wn + j * 16 + ln) * 64;

    f32x4 acc[8][4];
#pragma unroll
    for (int i = 0; i < 8; ++i)
#pragma unroll
        for (int j = 0; j < 4; ++j)
            acc[i][j] = (f32x4){0.f, 0.f, 0.f, 0.f};

    bf16x8 xf[8];           // X frags [nt*2+kh], live whole chunk (32 VGPR)
    bf16x8 afa[4], afb[4];  // A pair double-buffer [(row&1)*2+kh] (16+16 VGPR)

#define STAGE_CHUNK(c, SLOT) do {                                               \
    const int st_ = (c) >> 1, hs_ = (c) & 1;                                    \
    const int c0_ = (st_ >= 9) ? 128 : 0;                                       \
    const int kp_ = st_ - ((st_ >= 9) ? 9 : 0);                                 \
    const int dh_ = kp_ / 3 - 1;                                                \
    const int dw_ = kp_ - (dh_ + 1) * 3 - 1;                                    \
    const int aoff_ = kp_ * 256 + c0_ + hs_ * 64;                               \
    _Pragma("unroll")                                                           \
    for (int i = 0; i < 4; ++i)                                                 \
        __builtin_amdgcn_global_load_lds(AS1CAST(abase[i] + aoff_),             \
                                         AS3CAST(&As[SLOT][doff[i]]), 16, 0, 0);\
    _Pragma("unroll")                                                           \
    for (int i = 0; i < 4; ++i) {                                               \
        int h2_ = xh[i] + dh_, w2_ = xw[i] + dw_;                               \
        int row_ = ((unsigned)h2_ < (unsigned)HWDIM &&                          \
                    (unsigned)w2_ < (unsigned)HWDIM)                            \
                       ? (ximg[i] + h2_ * HWDIM + w2_) : NPIX;                  \
        __builtin_amdgcn_global_load_lds(                                       \
            AS1CAST(xt + (size_t)row_ * CIN + c0_ + hs_ * 64 + g * 8),          \
            AS3CAST(&Xs[SLOT][doff[i]]), 16, 0, 0);                             \
    }                                                                           \
} while (0)

#define READ_X(P) do {                                                          \
    _Pragma("unroll")                                                           \
    for (int n = 0; n < 4; ++n) {                                               \
        xf[n * 2 + 0] = *(const bf16x8*)&Xs[P][xrow[n] + so0];                  \
        xf[n * 2 + 1] = *(const bf16x8*)&Xs[P][xrow[n] + (so0 ^ 32)];           \
    }                                                                           \
} while (0)

// read A rows 2q, 2q+1 (both k-halves) into BUF[0..3]
#define READ_A2(P, q, BUF) do {                                                 \
    BUF[0] = *(const bf16x8*)&As[P][arow[2 * (q) + 0] + so0];                    \
    BUF[1] = *(const bf16x8*)&As[P][arow[2 * (q) + 0] + (so0 ^ 32)];             \
    BUF[2] = *(const bf16x8*)&As[P][arow[2 * (q) + 1] + so0];                    \
    BUF[3] = *(const bf16x8*)&As[P][arow[2 * (q) + 1] + (so0 ^ 32)];             \
} while (0)

// 16 MFMA: m-rows 2q..2q+1 x 4 n x 2 kh, frags from BUF
#define MFMA_PAIR(BUF, q) do {                                                  \
    __builtin_amdgcn_s_setprio(1);                                              \
    _Pragma("unroll")                                                           \
    for (int mloc = 0; mloc < 2; ++mloc)                                        \
        _Pragma("unroll")                                                       \
        for (int n = 0; n < 4; ++n) {                                           \
            acc[2 * (q) + mloc][n] = __builtin_amdgcn_mfma_f32_16x16x32_bf16(   \
                BUF[mloc * 2 + 0], xf[n * 2 + 0], acc[2 * (q) + mloc][n], 0, 0, 0);\
            acc[2 * (q) + mloc][n] = __builtin_amdgcn_mfma_f32_16x16x32_bf16(   \
                BUF[mloc * 2 + 1], xf[n * 2 + 1], acc[2 * (q) + mloc][n], 0, 0, 0);\
        }                                                                       \
    __builtin_amdgcn_s_setprio(0);                                              \
} while (0)

#define BAR() do {                                                              \
    __builtin_amdgcn_s_barrier();                                               \
    asm volatile("" ::: "memory");                                              \
} while (0)

#define CHUNK(kc, P, DO_NEXT) do {                                              \
    READ_X(P);                                                                  \
    READ_A2(P, 0, afa);                                                         \
    if (DO_NEXT) STAGE_CHUNK((kc) + 1, 1 - (P));                                \
    READ_A2(P, 1, afb);  MFMA_PAIR(afa, 0);   /* reads fly under MFMAs */       \
    READ_A2(P, 2, afa);  MFMA_PAIR(afb, 1);                                     \
    READ_A2(P, 3, afb);  MFMA_PAIR(afa, 2);                                     \
    MFMA_PAIR(afb, 3);                                                          \
    asm volatile("s_waitcnt lgkmcnt(0)" ::: "memory");  /* WAR cert (free) */   \
    if (DO_NEXT) asm volatile("s_waitcnt vmcnt(0)" ::: "memory"); /* RAW */     \
    BAR();   /* chunk boundary: certificates globalized */                      \
} while (0)

    // ---- prologue: stage chunk 0 -> slot 0; wait; sync
    STAGE_CHUNK(0, 0);
    asm volatile("s_waitcnt vmcnt(0)" ::: "memory");
    BAR();

    // ---- chunks 0..33 in parity pairs, then 34 (stages 35), then 35 (drains)
#pragma unroll 1
    for (int c = 0; c < 34; c += 2) {
        CHUNK(c, 0, 1);
        CHUNK(c + 1, 1, 1);
    }
    CHUNK(34, 0, 1);
    CHUNK(35, 1, 0);

#undef CHUNK
#undef BAR
#undef MFMA_PAIR
#undef READ_A2
#undef READ_X
#undef STAGE_CHUNK

    // epilogue: out[n][o][h][w] = alpha[o]*acc + bias[o]
#pragma unroll
    for (int im = 0; im < 8; ++im) {
        const int orow = wm + im * 16 + qd * 4;
        const f32x4 al = *(const f32x4*)&alpha[orow];
        const f32x4 bi = *(const f32x4*)&bias[orow];
#pragma unroll
        for (int in2 = 0; in2 < 4; ++in2) {
            const int pc = p0 + wn + in2 * 16 + ln;
            const int ni = pc / IMG;
            const int hwc = pc - ni * IMG;
            const size_t obase = (size_t)ni * COUT * IMG + hwc;
#pragma unroll
            for (int rr = 0; rr < 4; ++rr)
                out[obase + (size_t)(orow + rr) * IMG] = al[rr] * acc[im][in2][rr] + bi[rr];
        }
    }
}

extern "C" void kernel_launch(void* const* d_in, const int* in_sizes, int n_in,
                              void* d_out, int out_size, void* d_ws, size_t ws_size,
                              hipStream_t stream) {
    const float* x      = (const float*)d_in[0];
    const float* weight = (const float*)d_in[1];
    const float* bias   = (const float*)d_in[2];
    float* out = (float*)d_out;

    // workspace: xt (NPIX+1)*256 bf16 (last row = zero halo), wt2, alpha
    ushort_t* xt     = (ushort_t*)d_ws;
    ushort_t* wt2    = (ushort_t*)((char*)d_ws + (size_t)(NPIX + 1) * CIN * sizeof(ushort_t));
    float*    alphav = (float*)((char*)wt2 + (size_t)COUT * K_TOT * sizeof(ushort_t));

    ternarize_kernel<<<COUT, 256, 0, stream>>>(weight, wt2, alphav,
                                               xt + (size_t)NPIX * CIN);

    dim3 tg(IMG / 32, CIN / 128, NIMG);  // 98 x 2 x 32
    transpose_kernel<<<tg, 256, 0, stream>>>(x, xt);

    const int n_blocks = NPIX / BN;      // 392
    tern_conv_kernel<<<n_blocks, 512, 0, stream>>>(xt, wt2, alphav, bias, out);
}